// Round 1
// baseline (531.782 us; speedup 1.0000x reference)
//
#include <hip/hip_runtime.h>

// Problem dims
#define B_    32
#define CIN   32
#define COUT  64
#define H_    128
#define W_    128
#define HO_   126
#define WO_   126
#define MAXCN 64

// ---------------------------------------------------------------------------
// Kernel 1: fold the masked 64-slot kernel bank into a dense [COUT][CIN][9]
// kernel. slot j feeds channel j%32 and is active iff j < connect_nums[o].
// kd[o][c][t] = w[o][c][t]*(c<cn[o]) + w[o][c+32][t]*(c+32<cn[o])
// ---------------------------------------------------------------------------
__global__ void fold_kernel(const float* __restrict__ w,
                            const int* __restrict__ cn,
                            float* __restrict__ kd) {
    int idx = blockIdx.x * blockDim.x + threadIdx.x;
    if (idx >= COUT * CIN * 9) return;
    int t = idx % 9;
    int c = (idx / 9) % CIN;
    int o = idx / (9 * CIN);
    int n = cn[o];
    float v = 0.0f;
    if (c < n)       v += w[(o * MAXCN + c) * 9 + t];
    if (c + 32 < n)  v += w[(o * MAXCN + c + 32) * 9 + t];
    kd[idx] = v;
}

// ---------------------------------------------------------------------------
// Kernel 2: direct conv. Block = 256 threads.
//   blockIdx.z = batch, blockIdx.y = output-channel group (16 oc),
//   blockIdx.x = 8x8 spatial tiles of 16x16 output pixels.
// Thread tid: oc_l = tid&15 (output channel within group),
//             pb   = tid>>4 (one of 16 4x4 pixel sub-blocks).
// LDS: input tile [32][18][20] (pad 20 keeps float4 alignment + no conflicts;
//      x-reads broadcast across the 16 oc lanes), weights [16][289]
//      (stride 289 -> the 16 oc lanes hit 16 distinct banks).
// Per input channel: 36 x-values + 9 weights from LDS, 144 FMAs in regs.
// ---------------------------------------------------------------------------
__global__ __launch_bounds__(256)
void conv_kernel(const float* __restrict__ x,
                 const float* __restrict__ kd,
                 const float* __restrict__ bias,
                 float* __restrict__ out) {
    __shared__ __align__(16) float xs[CIN * 18 * 20];   // 46080 B
    __shared__ __align__(16) float ws[16 * 289];        // 18496 B

    const int b    = blockIdx.z;
    const int ocg  = blockIdx.y;
    const int tile = blockIdx.x;
    const int ty = tile >> 3, tx = tile & 7;
    const int y0 = ty * 16, x0 = tx * 16;
    const int tid = threadIdx.x;

    // ---- stage input tile (clamped at image edge; clamped values unused) ----
    const float* xb = x + (size_t)b * CIN * H_ * W_;
    for (int idx = tid; idx < CIN * 18 * 18; idx += 256) {
        int c   = idx / 324;
        int rem = idx - c * 324;
        int r   = rem / 18;
        int col = rem - r * 18;
        int iy = y0 + r;   if (iy > H_ - 1) iy = H_ - 1;
        int ix = x0 + col; if (ix > W_ - 1) ix = W_ - 1;
        xs[c * 360 + r * 20 + col] = xb[(c * H_ + iy) * W_ + ix];
    }
    // ---- stage folded weights for this oc group ----
    for (int idx = tid; idx < 16 * 288; idx += 256) {
        int oc = idx / 288;
        int rr = idx - oc * 288;
        ws[oc * 289 + rr] = kd[(ocg * 16 + oc) * 288 + rr];
    }
    __syncthreads();

    const int oc_l = tid & 15;
    const int pb   = tid >> 4;
    const int pby  = pb >> 2, pbx = pb & 3;

    float acc[4][4];
#pragma unroll
    for (int i = 0; i < 4; ++i)
#pragma unroll
        for (int j = 0; j < 4; ++j) acc[i][j] = 0.0f;

    const float* xp = &xs[(pby * 4) * 20 + pbx * 4];
    const float* wp = &ws[oc_l * 289];

    for (int c = 0; c < CIN; ++c) {
        float xr[6][6];
#pragma unroll
        for (int r = 0; r < 6; ++r) {
            const float* row = xp + c * 360 + r * 20;   // 16B aligned
            float4 v4 = *reinterpret_cast<const float4*>(row);
            float2 v2 = *reinterpret_cast<const float2*>(row + 4);
            xr[r][0] = v4.x; xr[r][1] = v4.y; xr[r][2] = v4.z;
            xr[r][3] = v4.w; xr[r][4] = v2.x; xr[r][5] = v2.y;
        }
        float wr[9];
#pragma unroll
        for (int t = 0; t < 9; ++t) wr[t] = wp[c * 9 + t];

#pragma unroll
        for (int kh = 0; kh < 3; ++kh)
#pragma unroll
            for (int kw = 0; kw < 3; ++kw) {
                const float wv = wr[kh * 3 + kw];
#pragma unroll
                for (int i = 0; i < 4; ++i)
#pragma unroll
                    for (int j = 0; j < 4; ++j)
                        acc[i][j] = fmaf(xr[i + kh][j + kw], wv, acc[i][j]);
            }
    }

    // ---- epilogue: + bias, guarded stores (126 not divisible by 16) ----
    const int o = ocg * 16 + oc_l;
    const int yb = y0 + pby * 4;
    const int xq0 = x0 + pbx * 4;
    float* ob = out + ((size_t)(b * COUT + o)) * HO_ * WO_;
    const float* bb = bias + (size_t)o * HO_ * WO_;
#pragma unroll
    for (int i = 0; i < 4; ++i) {
        int y = yb + i;
        if (y >= HO_) continue;
#pragma unroll
        for (int j = 0; j < 4; ++j) {
            int xq = xq0 + j;
            if (xq >= WO_) continue;
            ob[y * WO_ + xq] = acc[i][j] + bb[y * WO_ + xq];
        }
    }
}

extern "C" void kernel_launch(void* const* d_in, const int* in_sizes, int n_in,
                              void* d_out, int out_size, void* d_ws, size_t ws_size,
                              hipStream_t stream) {
    const float* x    = (const float*)d_in[0];
    const float* w    = (const float*)d_in[1];
    const float* bias = (const float*)d_in[2];
    const int*   cn   = (const int*)d_in[3];
    float* out = (float*)d_out;
    float* kd  = (float*)d_ws;   // 64*288*4 = 73728 B of scratch

    int total = COUT * CIN * 9;
    fold_kernel<<<(total + 255) / 256, 256, 0, stream>>>(w, cn, kd);

    dim3 grid(64, 4, B_);
    conv_kernel<<<grid, 256, 0, stream>>>(x, kd, bias, out);
}

// Round 2
// 278.292 us; speedup vs baseline: 1.9109x; 1.9109x over previous
//
#include <hip/hip_runtime.h>

// Problem dims
#define B_    32
#define CIN   32
#define COUT  64
#define H_    128
#define W_    128
#define HO_   126
#define WO_   126
#define MAXCN 64

typedef __attribute__((ext_vector_type(8))) short short8;
typedef __attribute__((ext_vector_type(4))) float floatx4;

static __device__ __forceinline__ unsigned short f2bf(float f) {
    union { float f; unsigned u; } v; v.f = f;
    unsigned r = v.u + 0x7fff + ((v.u >> 16) & 1);   // round-to-nearest-even
    return (unsigned short)(r >> 16);
}

// ---------------------------------------------------------------------------
// Fold masked 64-slot bank -> dense bf16 weights wk[tap][oc][c] (c-inner).
// slot j feeds channel j%32, active iff j < cn[oc].
// ---------------------------------------------------------------------------
__global__ void fold_bf16(const float* __restrict__ w,
                          const int* __restrict__ cn,
                          unsigned short* __restrict__ wk) {
    int idx = blockIdx.x * 256 + threadIdx.x;        // over 9*64*32 = 18432
    if (idx >= 9 * COUT * CIN) return;
    int c   = idx & 31;
    int oc  = (idx >> 5) & 63;
    int tap = idx >> 11;
    int n = cn[oc];
    float v = 0.0f;
    if (c < n)      v += w[(oc * MAXCN + c) * 9 + tap];
    if (c + 32 < n) v += w[(oc * MAXCN + c + 32) * 9 + tap];
    wk[idx] = f2bf(v);
}

// ---------------------------------------------------------------------------
// x [B][C][H][W] fp32  ->  xb [B][H][W][C] bf16 (NHWC). One block per (b,y).
// LDS pad 34 (stride 68 B, gcd(17,32)=1) -> conflict-free transpose.
// ---------------------------------------------------------------------------
__global__ __launch_bounds__(256)
void nchw_to_nhwc_bf16(const float* __restrict__ x,
                       unsigned short* __restrict__ xb) {
    __shared__ unsigned short tile[128 * 34];
    const int b = blockIdx.y, y = blockIdx.x;
    const int t = threadIdx.x;
    const int xi = t & 127, c0 = t >> 7;             // c0 in {0,1}
    const float* xp = x + ((size_t)(b * CIN) * H_ + y) * W_;
    for (int c = c0; c < CIN; c += 2) {
        float v = xp[(size_t)c * (H_ * W_) + xi];    // lanes -> consecutive xi
        tile[xi * 34 + c] = f2bf(v);
    }
    __syncthreads();
    unsigned short* op = xb + ((size_t)(b * H_ + y) * W_) * CIN;
    for (int k = t; k < W_ * CIN; k += 256) {        // consecutive bf16 writes
        int c = k & 31, x2 = k >> 5;
        op[k] = tile[x2 * 34 + c];
    }
}

// ---------------------------------------------------------------------------
// Implicit-GEMM conv, bf16 MFMA 16x16x32.
//   block: 16x16 output pixels x 64 oc for one batch image. 4 waves; wave w
//   owns output rows 4w..4w+3. Per tap: A = weights (m=oc), B = pixels
//   (n=col), K = 32 channels -> one mfma k-step; 9 taps total K=288.
//   acc[i][t]: i = row within wave, t = oc 16-tile. D: oc = 16t+quad*4+reg,
//   col = lane&15  -> quad-coalesced 64 B stores.
// LDS: xs[18][18][32] bf16 (rows copied as contiguous 1152 B from NHWC),
//      ws 9*64*32 bf16 (straight 36 KiB copy). Frag reads: addr =
//      const + l16*64B + quad*16B -> contiguous 1024 B/wave, conflict-free.
// ---------------------------------------------------------------------------
__global__ __launch_bounds__(256)
void conv_mfma(const unsigned short* __restrict__ xb,
               const unsigned short* __restrict__ wk,
               const float* __restrict__ bias,
               float* __restrict__ out) {
    __shared__ __align__(16) unsigned short xs[18 * 18 * 32];   // 20736 B
    __shared__ __align__(16) unsigned short ws[9 * 64 * 32];    // 36864 B

    const int tile = blockIdx.x;          // 0..63
    const int b    = blockIdx.y;
    const int tx = tile & 7, ty = tile >> 3;
    const int x0 = tx * 16, y0 = ty * 16;
    const int tid = threadIdx.x;

    // ---- stage input tile: 1296 uint4 (16 B = 8 channels of one (y,x)) ----
    uint4* xs4 = (uint4*)xs;
    for (int idx = tid; idx < 1296; idx += 256) {
        int yy = idx / 72;                 // 0..17
        int r  = idx - yy * 72;            // 0..71
        int xc = r >> 2;                   // col 0..17
        int cp = r & 3;                    // which 8-channel chunk
        int iy = y0 + yy; if (iy > H_ - 1) iy = H_ - 1;   // clamped rows feed
        int ix = x0 + xc; if (ix > W_ - 1) ix = W_ - 1;   // only unstored out
        const uint4* s = (const uint4*)(xb + (((size_t)b * H_ + iy) * W_ + ix) * CIN) + cp;
        xs4[idx] = *s;
    }
    // ---- stage all folded weights: 2304 uint4 linear copy ----
    uint4* ws4 = (uint4*)ws;
    const uint4* wk4 = (const uint4*)wk;
    for (int idx = tid; idx < 2304; idx += 256) ws4[idx] = wk4[idx];
    __syncthreads();

    const int w_id = tid >> 6;
    const int lane = tid & 63;
    const int quad = lane >> 4, l16 = lane & 15;

    floatx4 acc[4][4];
#pragma unroll
    for (int i = 0; i < 4; ++i)
#pragma unroll
        for (int t = 0; t < 4; ++t) acc[i][t] = (floatx4)0.0f;

#pragma unroll
    for (int kh = 0; kh < 3; ++kh) {
#pragma unroll
        for (int kw = 0; kw < 3; ++kw) {
            const int tap = kh * 3 + kw;
            short8 a[4], bf[4];
#pragma unroll
            for (int t = 0; t < 4; ++t)
                a[t] = *(const short8*)&ws[((tap * 64 + t * 16 + l16) * 32) + quad * 8];
#pragma unroll
            for (int i = 0; i < 4; ++i)
                bf[i] = *(const short8*)&xs[(((4 * w_id + i + kh) * 18 + l16 + kw) * 32) + quad * 8];
#pragma unroll
            for (int i = 0; i < 4; ++i)
#pragma unroll
                for (int t = 0; t < 4; ++t)
                    acc[i][t] = __builtin_amdgcn_mfma_f32_16x16x32_bf16(a[t], bf[i], acc[i][t], 0, 0, 0);
        }
    }

    // ---- epilogue: +bias, guarded coalesced stores ----
    const int col = x0 + l16;
#pragma unroll
    for (int i = 0; i < 4; ++i) {
        const int y = y0 + 4 * w_id + i;
        if (y >= HO_ || col >= WO_) continue;
#pragma unroll
        for (int t = 0; t < 4; ++t) {
#pragma unroll
            for (int r = 0; r < 4; ++r) {
                const int oc = t * 16 + quad * 4 + r;
                out[(((size_t)b * COUT + oc) * HO_ + y) * WO_ + col] =
                    acc[i][t][r] + bias[((size_t)oc * HO_ + y) * WO_ + col];
            }
        }
    }
}

// ===========================================================================
// Fallback fp32 path (proven in round 1) — used only if ws_size is too small
// for the 32 MiB NHWC buffer.
// ===========================================================================
__global__ void fold_kernel(const float* __restrict__ w,
                            const int* __restrict__ cn,
                            float* __restrict__ kd) {
    int idx = blockIdx.x * blockDim.x + threadIdx.x;
    if (idx >= COUT * CIN * 9) return;
    int t = idx % 9;
    int c = (idx / 9) % CIN;
    int o = idx / (9 * CIN);
    int n = cn[o];
    float v = 0.0f;
    if (c < n)      v += w[(o * MAXCN + c) * 9 + t];
    if (c + 32 < n) v += w[(o * MAXCN + c + 32) * 9 + t];
    kd[idx] = v;
}

__global__ __launch_bounds__(256)
void conv_kernel(const float* __restrict__ x,
                 const float* __restrict__ kd,
                 const float* __restrict__ bias,
                 float* __restrict__ out) {
    __shared__ __align__(16) float xsh[CIN * 18 * 20];
    __shared__ __align__(16) float wsh[16 * 289];
    const int b = blockIdx.z, ocg = blockIdx.y, tile = blockIdx.x;
    const int ty = tile >> 3, txx = tile & 7;
    const int y0 = ty * 16, x0 = txx * 16;
    const int tid = threadIdx.x;
    const float* xbp = x + (size_t)b * CIN * H_ * W_;
    for (int idx = tid; idx < CIN * 18 * 18; idx += 256) {
        int c = idx / 324, rem = idx - c * 324, r = rem / 18, col = rem - r * 18;
        int iy = y0 + r;   if (iy > H_ - 1) iy = H_ - 1;
        int ix = x0 + col; if (ix > W_ - 1) ix = W_ - 1;
        xsh[c * 360 + r * 20 + col] = xbp[(c * H_ + iy) * W_ + ix];
    }
    for (int idx = tid; idx < 16 * 288; idx += 256) {
        int oc = idx / 288, rr = idx - oc * 288;
        wsh[oc * 289 + rr] = kd[(ocg * 16 + oc) * 288 + rr];
    }
    __syncthreads();
    const int oc_l = tid & 15, pb = tid >> 4, pby = pb >> 2, pbx = pb & 3;
    float acc[4][4];
#pragma unroll
    for (int i = 0; i < 4; ++i)
#pragma unroll
        for (int j = 0; j < 4; ++j) acc[i][j] = 0.0f;
    const float* xp = &xsh[(pby * 4) * 20 + pbx * 4];
    const float* wp = &wsh[oc_l * 289];
    for (int c = 0; c < CIN; ++c) {
        float xr[6][6];
#pragma unroll
        for (int r = 0; r < 6; ++r) {
            const float* row = xp + c * 360 + r * 20;
            float4 v4 = *reinterpret_cast<const float4*>(row);
            float2 v2 = *reinterpret_cast<const float2*>(row + 4);
            xr[r][0] = v4.x; xr[r][1] = v4.y; xr[r][2] = v4.z;
            xr[r][3] = v4.w; xr[r][4] = v2.x; xr[r][5] = v2.y;
        }
        float wr[9];
#pragma unroll
        for (int t = 0; t < 9; ++t) wr[t] = wp[c * 9 + t];
#pragma unroll
        for (int kh = 0; kh < 3; ++kh)
#pragma unroll
            for (int kw = 0; kw < 3; ++kw) {
                const float wv = wr[kh * 3 + kw];
#pragma unroll
                for (int i = 0; i < 4; ++i)
#pragma unroll
                    for (int j = 0; j < 4; ++j)
                        acc[i][j] = fmaf(xr[i + kh][j + kw], wv, acc[i][j]);
            }
    }
    const int o = ocg * 16 + oc_l;
    const int yb = y0 + pby * 4, xq0 = x0 + pbx * 4;
    float* ob = out + ((size_t)(b * COUT + o)) * HO_ * WO_;
    const float* bb = bias + (size_t)o * HO_ * WO_;
#pragma unroll
    for (int i = 0; i < 4; ++i) {
        int y = yb + i;
        if (y >= HO_) continue;
#pragma unroll
        for (int j = 0; j < 4; ++j) {
            int xq = xq0 + j;
            if (xq >= WO_) continue;
            ob[y * WO_ + xq] = acc[i][j] + bb[y * WO_ + xq];
        }
    }
}

extern "C" void kernel_launch(void* const* d_in, const int* in_sizes, int n_in,
                              void* d_out, int out_size, void* d_ws, size_t ws_size,
                              hipStream_t stream) {
    const float* x    = (const float*)d_in[0];
    const float* w    = (const float*)d_in[1];
    const float* bias = (const float*)d_in[2];
    const int*   cn   = (const int*)d_in[3];
    float* out = (float*)d_out;

    const size_t XB_BYTES = (size_t)B_ * H_ * W_ * CIN * 2;   // 33554432
    const size_t WK_BYTES = (size_t)9 * COUT * CIN * 2;       // 36864

    if (ws_size >= XB_BYTES + WK_BYTES) {
        unsigned short* xbuf = (unsigned short*)d_ws;
        unsigned short* wkb  = (unsigned short*)((char*)d_ws + XB_BYTES);
        fold_bf16<<<(9 * COUT * CIN + 255) / 256, 256, 0, stream>>>(w, cn, wkb);
        nchw_to_nhwc_bf16<<<dim3(H_, B_), 256, 0, stream>>>(x, xbuf);
        conv_mfma<<<dim3(64, B_), 256, 0, stream>>>(xbuf, wkb, bias, out);
    } else {
        float* kd = (float*)d_ws;                             // 73728 B
        fold_kernel<<<(COUT * CIN * 9 + 255) / 256, 256, 0, stream>>>(w, cn, kd);
        dim3 grid(64, 4, B_);
        conv_kernel<<<grid, 256, 0, stream>>>(x, kd, bias, out);
    }
}

// Round 3
// 268.066 us; speedup vs baseline: 1.9838x; 1.0381x over previous
//
#include <hip/hip_runtime.h>

// Problem dims
#define B_    32
#define CIN   32
#define COUT  64
#define H_    128
#define W_    128
#define HO_   126
#define WO_   126
#define MAXCN 64

typedef __attribute__((ext_vector_type(8))) short short8;
typedef __attribute__((ext_vector_type(4))) float floatx4;

static __device__ __forceinline__ unsigned short f2bf(float f) {
    union { float f; unsigned u; } v; v.f = f;
    unsigned r = v.u + 0x7fff + ((v.u >> 16) & 1);   // round-to-nearest-even
    return (unsigned short)(r >> 16);
}

// ---------------------------------------------------------------------------
// Fold masked 64-slot bank -> dense bf16 weights wk[tap][oc][c] (c-inner).
// slot j feeds channel j%32, active iff j < cn[oc].
// ---------------------------------------------------------------------------
__global__ void fold_bf16(const float* __restrict__ w,
                          const int* __restrict__ cn,
                          unsigned short* __restrict__ wk) {
    int idx = blockIdx.x * 256 + threadIdx.x;        // over 9*64*32 = 18432
    if (idx >= 9 * COUT * CIN) return;
    int c   = idx & 31;
    int oc  = (idx >> 5) & 63;
    int tap = idx >> 11;
    int n = cn[oc];
    float v = 0.0f;
    if (c < n)      v += w[(oc * MAXCN + c) * 9 + tap];
    if (c + 32 < n) v += w[(oc * MAXCN + c + 32) * 9 + tap];
    wk[idx] = f2bf(v);
}

// ---------------------------------------------------------------------------
// x [B][C][H][W] fp32 -> xb [B][H][W][C] bf16 (NHWC). LDS-free:
// thread = (pixel xi, channel-octet c8). 8 loads, each instr covers 4
// distinct 64 B cache lines (16 lanes x consecutive xi) -> full-line
// efficiency. One uint4 store; wave's 64 stores = contiguous 1024 B.
// ---------------------------------------------------------------------------
__global__ __launch_bounds__(256)
void nchw_to_nhwc_bf16(const float* __restrict__ x,
                       unsigned short* __restrict__ xb) {
    const int b = blockIdx.y, y = blockIdx.x;
    const int t = threadIdx.x;
    const int c8  = t & 3;
    const int xi0 = t >> 2;                          // 0..63
    const float* xp = x + (size_t)b * CIN * H_ * W_ + (size_t)y * W_;
#pragma unroll
    for (int it = 0; it < 2; ++it) {
        const int xi = xi0 + it * 64;
        __align__(16) unsigned short v[8];
#pragma unroll
        for (int j = 0; j < 8; ++j) {
            const int c = c8 * 8 + j;
            v[j] = f2bf(xp[(size_t)c * (H_ * W_) + xi]);
        }
        *(uint4*)(xb + (((size_t)b * H_ + y) * W_ + xi) * CIN + c8 * 8) =
            *(const uint4*)v;
    }
}

// ---------------------------------------------------------------------------
// Implicit-GEMM conv, bf16 MFMA 16x16x32.
//   block: 16x16 output pixels x 32 oc (ocg = blockIdx.y). 4 waves; wave w
//   owns output rows 4w..4w+3. Per tap: A = weights (m=oc), B = pixels
//   (n=col), K = 32 channels; 9 taps -> K=288 total. acc[row][2 oc-tiles].
// LDS: xs[18][18][32] bf16 20736 B + ws[9][32][32] bf16 18432 B = 39168 B
//   -> 4 blocks/CU (vs 2 in R2) — the occupancy fix for the latency bound.
// All LDS frag reads: const + l16*64B + quad*16B -> contiguous 1 KiB/wave.
// ---------------------------------------------------------------------------
__global__ __launch_bounds__(256)
void conv_mfma(const unsigned short* __restrict__ xb,
               const unsigned short* __restrict__ wk,
               const float* __restrict__ bias,
               float* __restrict__ out) {
    __shared__ __align__(16) unsigned short xs[18 * 18 * 32];   // 20736 B
    __shared__ __align__(16) unsigned short ws[9 * 32 * 32];    // 18432 B

    const int tile = blockIdx.x;          // 0..63
    const int ocg  = blockIdx.y;          // 0..1
    const int b    = blockIdx.z;
    const int tx = tile & 7, ty = tile >> 3;
    const int x0 = tx * 16, y0 = ty * 16;
    const int tid = threadIdx.x;

    // ---- stage input tile: 1296 uint4 (16 B = 8 channels of one (y,x)) ----
    uint4* xs4 = (uint4*)xs;
    for (int idx = tid; idx < 1296; idx += 256) {
        int yy = idx / 72;                 // 0..17
        int r  = idx - yy * 72;
        int xc = r >> 2;                   // col 0..17
        int cp = r & 3;                    // channel-octet pair
        int iy = y0 + yy; if (iy > H_ - 1) iy = H_ - 1;   // clamped rows feed
        int ix = x0 + xc; if (ix > W_ - 1) ix = W_ - 1;   // only unstored out
        const uint4* s = (const uint4*)(xb + (((size_t)b * H_ + iy) * W_ + ix) * CIN) + cp;
        xs4[idx] = *s;
    }
    // ---- stage this oc-group's weights: 1152 uint4 ----
    uint4* ws4 = (uint4*)ws;
    const uint4* wk4 = (const uint4*)wk;
    for (int idx = tid; idx < 1152; idx += 256) {
        int tap  = idx >> 7;               // /128
        int rem  = idx & 127;
        int oc_l = rem >> 2;
        int cp   = rem & 3;
        ws4[idx] = wk4[tap * 256 + (ocg * 32 + oc_l) * 4 + cp];
    }
    __syncthreads();

    const int w_id = tid >> 6;
    const int lane = tid & 63;
    const int quad = lane >> 4, l16 = lane & 15;

    floatx4 acc[4][2];
#pragma unroll
    for (int i = 0; i < 4; ++i)
#pragma unroll
        for (int t = 0; t < 2; ++t) acc[i][t] = (floatx4)0.0f;

#pragma unroll
    for (int kh = 0; kh < 3; ++kh) {
#pragma unroll
        for (int kw = 0; kw < 3; ++kw) {
            const int tap = kh * 3 + kw;
            short8 a[2], bf[4];
#pragma unroll
            for (int t = 0; t < 2; ++t)
                a[t] = *(const short8*)&ws[((tap * 32 + t * 16 + l16) * 32) + quad * 8];
#pragma unroll
            for (int i = 0; i < 4; ++i)
                bf[i] = *(const short8*)&xs[(((4 * w_id + i + kh) * 18 + l16 + kw) * 32) + quad * 8];
#pragma unroll
            for (int i = 0; i < 4; ++i)
#pragma unroll
                for (int t = 0; t < 2; ++t)
                    acc[i][t] = __builtin_amdgcn_mfma_f32_16x16x32_bf16(a[t], bf[i], acc[i][t], 0, 0, 0);
        }
    }

    // ---- epilogue: +bias, guarded stores (quad-coalesced 64 B segments) ----
    const int col = x0 + l16;
#pragma unroll
    for (int i = 0; i < 4; ++i) {
        const int y = y0 + 4 * w_id + i;
        if (y >= HO_ || col >= WO_) continue;
#pragma unroll
        for (int t = 0; t < 2; ++t) {
#pragma unroll
            for (int r = 0; r < 4; ++r) {
                const int oc = ocg * 32 + t * 16 + quad * 4 + r;
                out[(((size_t)b * COUT + oc) * HO_ + y) * WO_ + col] =
                    acc[i][t][r] + bias[((size_t)oc * HO_ + y) * WO_ + col];
            }
        }
    }
}

// ===========================================================================
// Fallback fp32 path (proven in round 1) — used only if ws_size is too small
// for the 32 MiB NHWC buffer.
// ===========================================================================
__global__ void fold_kernel(const float* __restrict__ w,
                            const int* __restrict__ cn,
                            float* __restrict__ kd) {
    int idx = blockIdx.x * blockDim.x + threadIdx.x;
    if (idx >= COUT * CIN * 9) return;
    int t = idx % 9;
    int c = (idx / 9) % CIN;
    int o = idx / (9 * CIN);
    int n = cn[o];
    float v = 0.0f;
    if (c < n)      v += w[(o * MAXCN + c) * 9 + t];
    if (c + 32 < n) v += w[(o * MAXCN + c + 32) * 9 + t];
    kd[idx] = v;
}

__global__ __launch_bounds__(256)
void conv_kernel(const float* __restrict__ x,
                 const float* __restrict__ kd,
                 const float* __restrict__ bias,
                 float* __restrict__ out) {
    __shared__ __align__(16) float xsh[CIN * 18 * 20];
    __shared__ __align__(16) float wsh[16 * 289];
    const int b = blockIdx.z, ocg = blockIdx.y, tile = blockIdx.x;
    const int ty = tile >> 3, txx = tile & 7;
    const int y0 = ty * 16, x0 = txx * 16;
    const int tid = threadIdx.x;
    const float* xbp = x + (size_t)b * CIN * H_ * W_;
    for (int idx = tid; idx < CIN * 18 * 18; idx += 256) {
        int c = idx / 324, rem = idx - c * 324, r = rem / 18, col = rem - r * 18;
        int iy = y0 + r;   if (iy > H_ - 1) iy = H_ - 1;
        int ix = x0 + col; if (ix > W_ - 1) ix = W_ - 1;
        xsh[c * 360 + r * 20 + col] = xbp[(c * H_ + iy) * W_ + ix];
    }
    for (int idx = tid; idx < 16 * 288; idx += 256) {
        int oc = idx / 288, rr = idx - oc * 288;
        wsh[oc * 289 + rr] = kd[(ocg * 16 + oc) * 288 + rr];
    }
    __syncthreads();
    const int oc_l = tid & 15, pb = tid >> 4, pby = pb >> 2, pbx = pb & 3;
    float acc[4][4];
#pragma unroll
    for (int i = 0; i < 4; ++i)
#pragma unroll
        for (int j = 0; j < 4; ++j) acc[i][j] = 0.0f;
    const float* xp = &xsh[(pby * 4) * 20 + pbx * 4];
    const float* wp = &wsh[oc_l * 289];
    for (int c = 0; c < CIN; ++c) {
        float xr[6][6];
#pragma unroll
        for (int r = 0; r < 6; ++r) {
            const float* row = xp + c * 360 + r * 20;
            float4 v4 = *reinterpret_cast<const float4*>(row);
            float2 v2 = *reinterpret_cast<const float2*>(row + 4);
            xr[r][0] = v4.x; xr[r][1] = v4.y; xr[r][2] = v4.z;
            xr[r][3] = v4.w; xr[r][4] = v2.x; xr[r][5] = v2.y;
        }
        float wr[9];
#pragma unroll
        for (int t = 0; t < 9; ++t) wr[t] = wp[c * 9 + t];
#pragma unroll
        for (int kh = 0; kh < 3; ++kh)
#pragma unroll
            for (int kw = 0; kw < 3; ++kw) {
                const float wv = wr[kh * 3 + kw];
#pragma unroll
                for (int i = 0; i < 4; ++i)
#pragma unroll
                    for (int j = 0; j < 4; ++j)
                        acc[i][j] = fmaf(xr[i + kh][j + kw], wv, acc[i][j]);
            }
    }
    const int o = ocg * 16 + oc_l;
    const int yb = y0 + pby * 4, xq0 = x0 + pbx * 4;
    float* ob = out + ((size_t)(b * COUT + o)) * HO_ * WO_;
    const float* bb = bias + (size_t)o * HO_ * WO_;
#pragma unroll
    for (int i = 0; i < 4; ++i) {
        int y = yb + i;
        if (y >= HO_) continue;
#pragma unroll
        for (int j = 0; j < 4; ++j) {
            int xq = xq0 + j;
            if (xq >= WO_) continue;
            ob[y * WO_ + xq] = acc[i][j] + bb[y * WO_ + xq];
        }
    }
}

extern "C" void kernel_launch(void* const* d_in, const int* in_sizes, int n_in,
                              void* d_out, int out_size, void* d_ws, size_t ws_size,
                              hipStream_t stream) {
    const float* x    = (const float*)d_in[0];
    const float* w    = (const float*)d_in[1];
    const float* bias = (const float*)d_in[2];
    const int*   cn   = (const int*)d_in[3];
    float* out = (float*)d_out;

    const size_t XB_BYTES = (size_t)B_ * H_ * W_ * CIN * 2;   // 33554432
    const size_t WK_BYTES = (size_t)9 * COUT * CIN * 2;       // 36864

    if (ws_size >= XB_BYTES + WK_BYTES) {
        unsigned short* xbuf = (unsigned short*)d_ws;
        unsigned short* wkb  = (unsigned short*)((char*)d_ws + XB_BYTES);
        fold_bf16<<<(9 * COUT * CIN + 255) / 256, 256, 0, stream>>>(w, cn, wkb);
        nchw_to_nhwc_bf16<<<dim3(H_, B_), 256, 0, stream>>>(x, xbuf);
        conv_mfma<<<dim3(64, 2, B_), 256, 0, stream>>>(xbuf, wkb, bias, out);
    } else {
        float* kd = (float*)d_ws;                             // 73728 B
        fold_kernel<<<(COUT * CIN * 9 + 255) / 256, 256, 0, stream>>>(w, cn, kd);
        dim3 grid(64, 4, B_);
        conv_kernel<<<grid, 256, 0, stream>>>(x, kd, bias, out);
    }
}